// Round 7
// baseline (449.829 us; speedup 1.0000x reference)
//
#include <hip/hip_runtime.h>
#include <hip/hip_bf16.h>
#include <math.h>

#define N_NODES  50000
#define N_EDGES  800000
#define HIDDEN   256
#define HEADS    8
#define HEAD_DIM 32
#define MAXDEG   64
#define KVSTRIDE 512               // K row | V row interleaved per node
#define ROW_TILES (N_NODES / 16)   // 3125 exact

using short8 = __attribute__((ext_vector_type(8))) short;
using f32x4  = __attribute__((ext_vector_type(4))) float;

__device__ __forceinline__ float b2f(unsigned short u) {
  union { unsigned int i; float f; } v; v.i = ((unsigned int)u) << 16; return v.f;
}
__device__ __forceinline__ unsigned short f2b(float f) {
  union { float f; unsigned int i; } v; v.f = f;
  unsigned int r = v.i + 0x7FFF + ((v.i >> 16) & 1);   // round-to-nearest-even
  return (unsigned short)(r >> 16);
}

// ---- dtype detection: flags[0]=1 if float tensors are fp32; flags[1]=1 if idx int64
__global__ __launch_bounds__(256) void detect(const unsigned short* __restrict__ h16,
                                              const int* __restrict__ rowraw,
                                              int* __restrict__ flags) {
  __shared__ int nan_cnt, hi_viol, lo_pos;
  const int tid = threadIdx.x;
  if (tid == 0) { nan_cnt = 0; hi_viol = 0; lo_pos = 0; }
  __syncthreads();
  int local = 0;
  for (int i = tid; i < 16384; i += 256)
    if ((h16[i] & 0x7F80) == 0x7F80) local++;   // bf16 NaN/Inf pattern: ~1/256 if fp32
  if (local) atomicAdd(&nan_cnt, local);
  int viol = 0, pos = 0;
  for (int e = tid; e < 512; e += 256) {
    if (rowraw[2 * e + 1] != 0) viol++;
    if (rowraw[2 * e] > 0) pos++;
  }
  if (viol) atomicAdd(&hi_viol, viol);
  if (pos) atomicAdd(&lo_pos, pos);
  __syncthreads();
  if (tid == 0) {
    flags[0] = (nan_cnt >= 4) ? 1 : 0;
    flags[1] = (hi_viol == 0 && lo_pos > 0) ? 1 : 0;
  }
}

// Weights + biases, one launch.
// Wq/Wk/Wv: ROW-permuted so the GEMM's natural output IS head-major:
//   WP[g][k] = W[(g&31)*8 + (g>>5)][k]; bias likewise.
// Wo: K-DIM permuted (reads head-major pre): WoP[f][g] = Wo[f][(g&31)*8+(g>>5)].
struct WPtrs {
  const void* srcW[4]; unsigned short* dstW[4];
  const void* srcB[4]; unsigned short* dstB[4];
};
__global__ __launch_bounds__(256) void conv_wb(WPtrs p, const int* __restrict__ flags) {
  const int fp32 = flags[0];
  const int idx = blockIdx.x * 256 + threadIdx.x;
  if (idx < 49152) {                       // Wq,Wk,Wv: vec4 along k, row-permuted
    const int m = idx >> 14, r = idx & 16383;
    const int g = r >> 6, kc = r & 63;
    const int f = ((g & 31) << 3) | (g >> 5);   // source row
    const int s = f * 64 + kc;
    if (fp32) {
      const float4 v = ((const float4*)p.srcW[m])[s];
      ushort4 o; o.x = f2b(v.x); o.y = f2b(v.y); o.z = f2b(v.z); o.w = f2b(v.w);
      ((ushort4*)p.dstW[m])[g * 64 + kc] = o;
    } else {
      ((ushort4*)p.dstW[m])[g * 64 + kc] = ((const ushort4*)p.srcW[m])[s];
    }
  } else if (idx < 49152 + 65536) {        // Wo: scalar, permuted k index
    const int g = idx - 49152;
    const int f = g >> 8, kk = g & 255;
    const int s = f * 256 + (((kk & 31) << 3) | (kk >> 5));
    p.dstW[3][g] = fp32 ? f2b(((const float*)p.srcW[3])[s])
                        : ((const unsigned short*)p.srcW[3])[s];
  } else if (idx < 49152 + 65536 + 256) {  // biases
    const int t = idx - 49152 - 65536;
    const int m = t >> 6, r = t & 63;
    if (m < 3) {
      ushort4 o;
      #pragma unroll
      for (int x = 0; x < 4; ++x) {
        const int g = r * 4 + x;
        const int f = ((g & 31) << 3) | (g >> 5);
        ((unsigned short*)&o)[x] = fp32 ? f2b(((const float*)p.srcB[m])[f])
                                        : ((const unsigned short*)p.srcB[m])[f];
      }
      ((ushort4*)p.dstB[m])[r] = o;
    } else {
      if (fp32) {
        const float4 v = ((const float4*)p.srcB[3])[r];
        ushort4 o; o.x = f2b(v.x); o.y = f2b(v.y); o.z = f2b(v.z); o.w = f2b(v.w);
        ((ushort4*)p.dstB[3])[r] = o;
      } else {
        ((ushort4*)p.dstB[3])[r] = ((const ushort4*)p.srcB[3])[r];
      }
    }
  }
}

// bucket build with fused index conversion; bucket stores converted col
__global__ __launch_bounds__(256) void build_buckets(
    const int* __restrict__ rowraw, const int* __restrict__ colraw,
    const int* __restrict__ flags, int* __restrict__ cursor, int* __restrict__ bucket)
{
  const int e = blockIdx.x * 256 + threadIdx.x;
  if (e >= N_EDGES) return;
  const int i64 = flags[1];
  const int r = i64 ? rowraw[2 * e] : rowraw[e];
  const int c = i64 ? colraw[2 * e] : colraw[e];
  const int pos = atomicAdd(&cursor[r], 1);
  if (pos < MAXDEG) bucket[r * MAXDEG + pos] = c;
}

// QKV projection. blockIdx.y = matrix (grid 391x3 => ~4.6 waves/SIMD).
// Reads RAW h (fp32 or bf16 per flags[0]); conversion fused into A-preload.
// Each wave: 2 row-tiles, 4 col-strips inner. Row-permuted weights => natural
// coalesced stores give head-major output.
struct QKVp {
  const unsigned short* W[3];
  const unsigned short* b[3];
  unsigned short* Y[3];
  int ldY[3];
};
__global__ __launch_bounds__(256) void gemm_qkv(
    const void* __restrict__ Xraw, QKVp p, float qscale, const int* __restrict__ flags)
{
  const int wid  = threadIdx.x >> 6;
  const int lane = threadIdx.x & 63;
  const int t0 = blockIdx.x * 8 + wid * 2;
  if (t0 >= ROW_TILES) return;
  int t1 = t0 + 1;
  const bool has1 = (t1 < ROW_TILES);
  if (!has1) t1 = t0;
  const int quad = lane >> 4, lrow = lane & 15;
  const int fp32 = flags[0];

  const int m = blockIdx.y;
  const unsigned short* __restrict__ W = p.W[m];
  const unsigned short* __restrict__ bias = p.b[m];
  unsigned short* __restrict__ Y = p.Y[m];
  const int ld = p.ldY[m];
  const float scale = (m == 0) ? qscale : 1.0f;

  // preload A fragments, converting fp32->bf16 if needed
  short8 A[2][8];
  {
    const size_t base0 = (size_t)(t0 * 16 + lrow) * HIDDEN + quad * 8;
    const size_t base1 = (size_t)(t1 * 16 + lrow) * HIDDEN + quad * 8;
    if (fp32) {
      const float* Xf = (const float*)Xraw;
      #pragma unroll
      for (int ks = 0; ks < 8; ++ks) {
        const float4 u0 = *(const float4*)(Xf + base0 + ks * 32);
        const float4 u1 = *(const float4*)(Xf + base0 + ks * 32 + 4);
        const float4 w0 = *(const float4*)(Xf + base1 + ks * 32);
        const float4 w1 = *(const float4*)(Xf + base1 + ks * 32 + 4);
        short8 s0, s1;
        s0[0]=(short)f2b(u0.x); s0[1]=(short)f2b(u0.y); s0[2]=(short)f2b(u0.z); s0[3]=(short)f2b(u0.w);
        s0[4]=(short)f2b(u1.x); s0[5]=(short)f2b(u1.y); s0[6]=(short)f2b(u1.z); s0[7]=(short)f2b(u1.w);
        s1[0]=(short)f2b(w0.x); s1[1]=(short)f2b(w0.y); s1[2]=(short)f2b(w0.z); s1[3]=(short)f2b(w0.w);
        s1[4]=(short)f2b(w1.x); s1[5]=(short)f2b(w1.y); s1[6]=(short)f2b(w1.z); s1[7]=(short)f2b(w1.w);
        A[0][ks] = s0; A[1][ks] = s1;
      }
    } else {
      const unsigned short* Xb = (const unsigned short*)Xraw;
      #pragma unroll
      for (int ks = 0; ks < 8; ++ks) {
        A[0][ks] = *(const short8*)(Xb + base0 + ks * 32);
        A[1][ks] = *(const short8*)(Xb + base1 + ks * 32);
      }
    }
  }

  for (int cs = 0; cs < 4; ++cs) {
    const int col0 = cs * 64;
    const short8* bp0 = (const short8*)(W + (size_t)(col0 +  0 + lrow) * HIDDEN + quad * 8);
    const short8* bp1 = (const short8*)(W + (size_t)(col0 + 16 + lrow) * HIDDEN + quad * 8);
    const short8* bp2 = (const short8*)(W + (size_t)(col0 + 32 + lrow) * HIDDEN + quad * 8);
    const short8* bp3 = (const short8*)(W + (size_t)(col0 + 48 + lrow) * HIDDEN + quad * 8);

    f32x4 acc[2][4];
    #pragma unroll
    for (int t = 0; t < 2; ++t)
      #pragma unroll
      for (int c = 0; c < 4; ++c) acc[t][c] = (f32x4){0.f, 0.f, 0.f, 0.f};

    #pragma unroll
    for (int ks = 0; ks < 8; ++ks) {
      const short8 b0 = bp0[ks * 4], b1 = bp1[ks * 4], b2 = bp2[ks * 4], b3 = bp3[ks * 4];
      acc[0][0] = __builtin_amdgcn_mfma_f32_16x16x32_bf16(A[0][ks], b0, acc[0][0], 0, 0, 0);
      acc[1][0] = __builtin_amdgcn_mfma_f32_16x16x32_bf16(A[1][ks], b0, acc[1][0], 0, 0, 0);
      acc[0][1] = __builtin_amdgcn_mfma_f32_16x16x32_bf16(A[0][ks], b1, acc[0][1], 0, 0, 0);
      acc[1][1] = __builtin_amdgcn_mfma_f32_16x16x32_bf16(A[1][ks], b1, acc[1][1], 0, 0, 0);
      acc[0][2] = __builtin_amdgcn_mfma_f32_16x16x32_bf16(A[0][ks], b2, acc[0][2], 0, 0, 0);
      acc[1][2] = __builtin_amdgcn_mfma_f32_16x16x32_bf16(A[1][ks], b2, acc[1][2], 0, 0, 0);
      acc[0][3] = __builtin_amdgcn_mfma_f32_16x16x32_bf16(A[0][ks], b3, acc[0][3], 0, 0, 0);
      acc[1][3] = __builtin_amdgcn_mfma_f32_16x16x32_bf16(A[1][ks], b3, acc[1][3], 0, 0, 0);
    }

    #pragma unroll
    for (int c = 0; c < 4; ++c) {
      const int f = col0 + c * 16 + lrow;
      const float bv = b2f(bias[f]);
      #pragma unroll
      for (int r = 0; r < 4; ++r) {
        const int i0 = t0 * 16 + quad * 4 + r;
        Y[(size_t)i0 * ld + f] = f2b((acc[0][c][r] + bv) * scale);
        if (has1) {
          const int i1 = t1 * 16 + quad * 4 + r;
          Y[(size_t)i1 * ld + f] = f2b((acc[1][c][r] + bv) * scale);
        }
      }
    }
  }
}

// Output projection: blockIdx.y = col-strip (grid 391x4 => ~6 waves/SIMD).
// A = pre (head-major bf16), W = WoP (k-dim pre-permuted).
__global__ __launch_bounds__(256) void gemm_o(
    const unsigned short* __restrict__ X, const unsigned short* __restrict__ W,
    const unsigned short* __restrict__ bias, void* __restrict__ Yv,
    const int* __restrict__ flags)
{
  const int wid  = threadIdx.x >> 6;
  const int lane = threadIdx.x & 63;
  const int t0 = blockIdx.x * 8 + wid * 2;
  if (t0 >= ROW_TILES) return;
  int t1 = t0 + 1;
  const bool has1 = (t1 < ROW_TILES);
  if (!has1) t1 = t0;
  const int quad = lane >> 4, lrow = lane & 15;
  const int out_fp32 = flags[0];

  short8 A[2][8];
  {
    const short8* a0p = (const short8*)(X + (size_t)(t0 * 16 + lrow) * HIDDEN + quad * 8);
    const short8* a1p = (const short8*)(X + (size_t)(t1 * 16 + lrow) * HIDDEN + quad * 8);
    #pragma unroll
    for (int ks = 0; ks < 8; ++ks) { A[0][ks] = a0p[ks * 4]; A[1][ks] = a1p[ks * 4]; }
  }

  const int col0 = blockIdx.y * 64;
  const short8* bp0 = (const short8*)(W + (size_t)(col0 +  0 + lrow) * HIDDEN + quad * 8);
  const short8* bp1 = (const short8*)(W + (size_t)(col0 + 16 + lrow) * HIDDEN + quad * 8);
  const short8* bp2 = (const short8*)(W + (size_t)(col0 + 32 + lrow) * HIDDEN + quad * 8);
  const short8* bp3 = (const short8*)(W + (size_t)(col0 + 48 + lrow) * HIDDEN + quad * 8);

  f32x4 acc[2][4];
  #pragma unroll
  for (int t = 0; t < 2; ++t)
    #pragma unroll
    for (int c = 0; c < 4; ++c) acc[t][c] = (f32x4){0.f, 0.f, 0.f, 0.f};

  #pragma unroll
  for (int ks = 0; ks < 8; ++ks) {
    const short8 b0 = bp0[ks * 4], b1 = bp1[ks * 4], b2 = bp2[ks * 4], b3 = bp3[ks * 4];
    acc[0][0] = __builtin_amdgcn_mfma_f32_16x16x32_bf16(A[0][ks], b0, acc[0][0], 0, 0, 0);
    acc[1][0] = __builtin_amdgcn_mfma_f32_16x16x32_bf16(A[1][ks], b0, acc[1][0], 0, 0, 0);
    acc[0][1] = __builtin_amdgcn_mfma_f32_16x16x32_bf16(A[0][ks], b1, acc[0][1], 0, 0, 0);
    acc[1][1] = __builtin_amdgcn_mfma_f32_16x16x32_bf16(A[1][ks], b1, acc[1][1], 0, 0, 0);
    acc[0][2] = __builtin_amdgcn_mfma_f32_16x16x32_bf16(A[0][ks], b2, acc[0][2], 0, 0, 0);
    acc[1][2] = __builtin_amdgcn_mfma_f32_16x16x32_bf16(A[1][ks], b2, acc[1][2], 0, 0, 0);
    acc[0][3] = __builtin_amdgcn_mfma_f32_16x16x32_bf16(A[0][ks], b3, acc[0][3], 0, 0, 0);
    acc[1][3] = __builtin_amdgcn_mfma_f32_16x16x32_bf16(A[1][ks], b3, acc[1][3], 0, 0, 0);
  }

  #pragma unroll
  for (int c = 0; c < 4; ++c) {
    const int f = col0 + c * 16 + lrow;
    const float bv = b2f(bias[f]);
    #pragma unroll
    for (int r = 0; r < 4; ++r) {
      const int i0 = t0 * 16 + quad * 4 + r;
      const float y0 = acc[0][c][r] + bv;
      if (out_fp32) ((float*)Yv)[(size_t)i0 * HIDDEN + f] = y0;
      else ((unsigned short*)Yv)[(size_t)i0 * HIDDEN + f] = f2b(y0);
      if (has1) {
        const int i1 = t1 * 16 + quad * 4 + r;
        const float y1 = acc[1][c][r] + bv;
        if (out_fp32) ((float*)Yv)[(size_t)i1 * HIDDEN + f] = y1;
        else ((unsigned short*)Yv)[(size_t)i1 * HIDDEN + f] = f2b(y1);
      }
    }
  }
}

// Fused SDDMM + exp + SPMM, normalization in epilogue. One wave per node.
// KV interleaved: node n -> [K row 256 | V row 256] at KV + n*512.
// Lane l owns head-major dims [4l,4l+4) (head = l>>3). Zero LDS/barriers.
// Unroll x2 with depth-2 prefetch: 4 K/V loads in flight.
__global__ __launch_bounds__(256) void attn_fused(
    const unsigned short* __restrict__ Qt, const unsigned short* __restrict__ KV,
    const int* __restrict__ cursor, const int* __restrict__ bucket,
    unsigned short* __restrict__ pre)
{
  const int node = blockIdx.x * 4 + (threadIdx.x >> 6);
  if (node >= N_NODES) return;
  const int lane = threadIdx.x & 63;
  int cnt = cursor[node]; if (cnt > MAXDEG) cnt = MAXDEG;
  const int* brow = bucket + node * MAXDEG;

  const ushort4 qv = *(const ushort4*)(Qt + (size_t)node * HIDDEN + lane * 4);
  const float q0 = b2f(qv.x), q1 = b2f(qv.y), q2 = b2f(qv.z), q3 = b2f(qv.w);

  float a0 = 0.f, a1 = 0.f, a2 = 0.f, a3 = 0.f, z = 0.f;

  if (cnt > 0) {
    const int last = cnt - 1;
    int c0 = brow[0];
    int c1 = brow[1 <= last ? 1 : last];
    ushort4 k0 = *(const ushort4*)(KV + (size_t)c0 * KVSTRIDE + lane * 4);
    ushort4 v0 = *(const ushort4*)(KV + (size_t)c0 * KVSTRIDE + 256 + lane * 4);
    ushort4 k1 = *(const ushort4*)(KV + (size_t)c1 * KVSTRIDE + lane * 4);
    ushort4 v1 = *(const ushort4*)(KV + (size_t)c1 * KVSTRIDE + 256 + lane * 4);

    int j = 0;
    for (; j + 2 <= cnt; j += 2) {
      const int c2 = brow[j + 2 <= last ? j + 2 : last];
      const int c3 = brow[j + 3 <= last ? j + 3 : last];
      const ushort4 k2 = *(const ushort4*)(KV + (size_t)c2 * KVSTRIDE + lane * 4);
      const ushort4 v2 = *(const ushort4*)(KV + (size_t)c2 * KVSTRIDE + 256 + lane * 4);
      const ushort4 k3 = *(const ushort4*)(KV + (size_t)c3 * KVSTRIDE + lane * 4);
      const ushort4 v3 = *(const ushort4*)(KV + (size_t)c3 * KVSTRIDE + 256 + lane * 4);

      float dA = q0 * b2f(k0.x) + q1 * b2f(k0.y) + q2 * b2f(k0.z) + q3 * b2f(k0.w);
      float dB = q0 * b2f(k1.x) + q1 * b2f(k1.y) + q2 * b2f(k1.z) + q3 * b2f(k1.w);
      dA += __shfl_xor(dA, 1, 64);  dB += __shfl_xor(dB, 1, 64);
      dA += __shfl_xor(dA, 2, 64);  dB += __shfl_xor(dB, 2, 64);
      dA += __shfl_xor(dA, 4, 64);  dB += __shfl_xor(dB, 4, 64);
      const float wA = __expf(dA);
      const float wB = __expf(dB);
      z  += wA + wB;
      a0 += wA * b2f(v0.x) + wB * b2f(v1.x);
      a1 += wA * b2f(v0.y) + wB * b2f(v1.y);
      a2 += wA * b2f(v0.z) + wB * b2f(v1.z);
      a3 += wA * b2f(v0.w) + wB * b2f(v1.w);

      k0 = k2; v0 = v2; k1 = k3; v1 = v3;
    }
    if (j < cnt) {   // odd tail
      float dA = q0 * b2f(k0.x) + q1 * b2f(k0.y) + q2 * b2f(k0.z) + q3 * b2f(k0.w);
      dA += __shfl_xor(dA, 1, 64);
      dA += __shfl_xor(dA, 2, 64);
      dA += __shfl_xor(dA, 4, 64);
      const float wA = __expf(dA);
      z  += wA;
      a0 += wA * b2f(v0.x); a1 += wA * b2f(v0.y);
      a2 += wA * b2f(v0.z); a3 += wA * b2f(v0.w);
    }
  }

  const float zi = (z > 0.f) ? (1.f / z) : 0.f;
  ushort4 o;
  o.x = f2b(a0 * zi); o.y = f2b(a1 * zi); o.z = f2b(a2 * zi); o.w = f2b(a3 * zi);
  *(ushort4*)(pre + (size_t)node * HIDDEN + lane * 4) = o;
}

extern "C" void kernel_launch(void* const* d_in, const int* in_sizes, int n_in,
                              void* d_out, int out_size, void* d_ws, size_t ws_size,
                              hipStream_t stream) {
  const void* h_raw  = d_in[0];
  const int* row_raw = (const int*)d_in[1];
  const int* col_raw = (const int*)d_in[2];
  const void* Wq_raw = d_in[3]; const void* bq_raw = d_in[4];
  const void* Wk_raw = d_in[5]; const void* bk_raw = d_in[6];
  const void* Wv_raw = d_in[7]; const void* bv_raw = d_in[8];
  const void* Wo_raw = d_in[9]; const void* bo_raw = d_in[10];

  char* ws = (char*)d_ws;
  unsigned short* Qt   = (unsigned short*)(ws +          0);  // 25.6 MB
  unsigned short* KV   = (unsigned short*)(ws +  25600000);   // 51.2 MB interleaved K|V
  int*            cur  = (int*)           (ws +  76800000);   // 0.2 MB
  int*            bkt  = (int*)           (ws +  77000000);   // 12.8 MB
  unsigned short* pre  = (unsigned short*)(ws +  89800000);   // 25.6 MB
  unsigned short* WqP  = (unsigned short*)(ws + 115400000);   // 4 x 128 KB
  unsigned short* WkP  = WqP + 65536;
  unsigned short* WvP  = WkP + 65536;
  unsigned short* WoP  = WvP + 65536;
  unsigned short* bqP  = (unsigned short*)(ws + 116000000);   // 4 x 512 B
  unsigned short* bkP  = bqP + 256;
  unsigned short* bvP  = bkP + 256;
  unsigned short* boC  = bvP + 256;
  int*            flags = (int*)(ws + 116100000);

  hipMemsetAsync(cur, 0, (size_t)N_NODES * 4, stream);

  detect<<<1, 256, 0, stream>>>((const unsigned short*)h_raw, row_raw, flags);

  WPtrs wp;
  wp.srcW[0] = Wq_raw; wp.srcW[1] = Wk_raw; wp.srcW[2] = Wv_raw; wp.srcW[3] = Wo_raw;
  wp.dstW[0] = WqP;    wp.dstW[1] = WkP;    wp.dstW[2] = WvP;    wp.dstW[3] = WoP;
  wp.srcB[0] = bq_raw; wp.srcB[1] = bk_raw; wp.srcB[2] = bv_raw; wp.srcB[3] = bo_raw;
  wp.dstB[0] = bqP;    wp.dstB[1] = bkP;    wp.dstB[2] = bvP;    wp.dstB[3] = boC;
  conv_wb<<<(114944 + 255) / 256, 256, 0, stream>>>(wp, flags);

  build_buckets<<<(N_EDGES + 255) / 256, 256, 0, stream>>>(row_raw, col_raw, flags, cur, bkt);

  QKVp qp;
  qp.W[0] = WqP; qp.W[1] = WkP; qp.W[2] = WvP;
  qp.b[0] = bqP; qp.b[1] = bkP; qp.b[2] = bvP;
  qp.Y[0] = Qt;  qp.Y[1] = KV;  qp.Y[2] = KV + 256;   // K at +0, V at +256, stride 512
  qp.ldY[0] = HIDDEN; qp.ldY[1] = KVSTRIDE; qp.ldY[2] = KVSTRIDE;
  dim3 qgrid((ROW_TILES + 7) / 8, 3);
  gemm_qkv<<<qgrid, 256, 0, stream>>>(h_raw, qp, 0.17677669529663687f, flags);

  attn_fused<<<(N_NODES + 3) / 4, 256, 0, stream>>>(Qt, KV, cur, bkt, pre);

  dim3 ogrid((ROW_TILES + 7) / 8, 4);
  gemm_o<<<ogrid, 256, 0, stream>>>(pre, WoP, boC, d_out, flags);
}

// Round 8
// 391.482 us; speedup vs baseline: 1.1490x; 1.1490x over previous
//
#include <hip/hip_runtime.h>
#include <hip/hip_bf16.h>
#include <math.h>

#define N_NODES  50000
#define N_EDGES  800000
#define HIDDEN   256
#define HEADS    8
#define HEAD_DIM 32
#define MAXDEG   64
#define KVSTRIDE 512               // K row | V row interleaved per node
#define MTILES   391               // ceil(50000 / 128)

using short8 = __attribute__((ext_vector_type(8))) short;
using f32x4  = __attribute__((ext_vector_type(4))) float;

__device__ __forceinline__ float b2f(unsigned short u) {
  union { unsigned int i; float f; } v; v.i = ((unsigned int)u) << 16; return v.f;
}
__device__ __forceinline__ unsigned short f2b(float f) {
  union { float f; unsigned int i; } v; v.f = f;
  unsigned int r = v.i + 0x7FFF + ((v.i >> 16) & 1);   // round-to-nearest-even
  return (unsigned short)(r >> 16);
}

// ---- dtype detection: flags[0]=1 if float tensors are fp32; flags[1]=1 if idx int64
__global__ __launch_bounds__(256) void detect(const unsigned short* __restrict__ h16,
                                              const int* __restrict__ rowraw,
                                              int* __restrict__ flags) {
  __shared__ int nan_cnt, hi_viol, lo_pos;
  const int tid = threadIdx.x;
  if (tid == 0) { nan_cnt = 0; hi_viol = 0; lo_pos = 0; }
  __syncthreads();
  int local = 0;
  for (int i = tid; i < 16384; i += 256)
    if ((h16[i] & 0x7F80) == 0x7F80) local++;   // bf16 NaN/Inf pattern: ~1/256 if fp32
  if (local) atomicAdd(&nan_cnt, local);
  int viol = 0, pos = 0;
  for (int e = tid; e < 512; e += 256) {
    if (rowraw[2 * e + 1] != 0) viol++;
    if (rowraw[2 * e] > 0) pos++;
  }
  if (viol) atomicAdd(&hi_viol, viol);
  if (pos) atomicAdd(&lo_pos, pos);
  __syncthreads();
  if (tid == 0) {
    flags[0] = (nan_cnt >= 4) ? 1 : 0;
    flags[1] = (hi_viol == 0 && lo_pos > 0) ? 1 : 0;
  }
}

// canonicalize h -> bf16 (copy if already bf16), 4 elements/thread
__global__ __launch_bounds__(256) void conv_f4(const void* __restrict__ src,
                                               unsigned short* __restrict__ dst, int n4,
                                               const int* __restrict__ flags) {
  const int fp32 = flags[0];
  for (int i = blockIdx.x * 256 + threadIdx.x; i < n4; i += gridDim.x * 256) {
    if (fp32) {
      const float4 v = ((const float4*)src)[i];
      ushort4 o; o.x = f2b(v.x); o.y = f2b(v.y); o.z = f2b(v.z); o.w = f2b(v.w);
      ((ushort4*)dst)[i] = o;
    } else {
      ((ushort4*)dst)[i] = ((const ushort4*)src)[i];
    }
  }
}

// Weights + biases, one launch.
// Wq/Wk/Wv: ROW-permuted (head-major outputs); Wo: K-DIM permuted.
struct WPtrs {
  const void* srcW[4]; unsigned short* dstW[4];
  const void* srcB[4]; unsigned short* dstB[4];
};
__global__ __launch_bounds__(256) void conv_wb(WPtrs p, const int* __restrict__ flags) {
  const int fp32 = flags[0];
  const int idx = blockIdx.x * 256 + threadIdx.x;
  if (idx < 49152) {                       // Wq,Wk,Wv: vec4 along k, row-permuted
    const int m = idx >> 14, r = idx & 16383;
    const int g = r >> 6, kc = r & 63;
    const int f = ((g & 31) << 3) | (g >> 5);   // source row
    const int s = f * 64 + kc;
    if (fp32) {
      const float4 v = ((const float4*)p.srcW[m])[s];
      ushort4 o; o.x = f2b(v.x); o.y = f2b(v.y); o.z = f2b(v.z); o.w = f2b(v.w);
      ((ushort4*)p.dstW[m])[g * 64 + kc] = o;
    } else {
      ((ushort4*)p.dstW[m])[g * 64 + kc] = ((const ushort4*)p.srcW[m])[s];
    }
  } else if (idx < 49152 + 65536) {        // Wo: scalar, permuted k index
    const int g = idx - 49152;
    const int f = g >> 8, kk = g & 255;
    const int s = f * 256 + (((kk & 31) << 3) | (kk >> 5));
    p.dstW[3][g] = fp32 ? f2b(((const float*)p.srcW[3])[s])
                        : ((const unsigned short*)p.srcW[3])[s];
  } else if (idx < 49152 + 65536 + 256) {  // biases
    const int t = idx - 49152 - 65536;
    const int m = t >> 6, r = t & 63;
    if (m < 3) {
      ushort4 o;
      #pragma unroll
      for (int x = 0; x < 4; ++x) {
        const int g = r * 4 + x;
        const int f = ((g & 31) << 3) | (g >> 5);
        ((unsigned short*)&o)[x] = fp32 ? f2b(((const float*)p.srcB[m])[f])
                                        : ((const unsigned short*)p.srcB[m])[f];
      }
      ((ushort4*)p.dstB[m])[r] = o;
    } else {
      if (fp32) {
        const float4 v = ((const float4*)p.srcB[3])[r];
        ushort4 o; o.x = f2b(v.x); o.y = f2b(v.y); o.z = f2b(v.z); o.w = f2b(v.w);
        ((ushort4*)p.dstB[3])[r] = o;
      } else {
        ((ushort4*)p.dstB[3])[r] = ((const ushort4*)p.srcB[3])[r];
      }
    }
  }
}

// bucket build with fused index conversion; bucket stores converted col
__global__ __launch_bounds__(256) void build_buckets(
    const int* __restrict__ rowraw, const int* __restrict__ colraw,
    const int* __restrict__ flags, int* __restrict__ cursor, int* __restrict__ bucket)
{
  const int e = blockIdx.x * 256 + threadIdx.x;
  if (e >= N_EDGES) return;
  const int i64 = flags[1];
  const int r = i64 ? rowraw[2 * e] : rowraw[e];
  const int c = i64 ? colraw[2 * e] : colraw[e];
  const int pos = atomicAdd(&cursor[r], 1);
  if (pos < MAXDEG) bucket[r * MAXDEG + pos] = c;
}

// ---- m97-style staging: 128x64 bf16 tile -> LDS [128][64], XOR-swizzled.
// Logical col-block cb (8 shorts) of row r stored at slot pb = cb ^ (r&7).
// global_load_lds dest = wave-uniform base + lane*16 (contiguous): lane l
// stages row chunk*8+(l>>3), slot l&7, whose SOURCE col-block is (l&7)^((l>>3)&7).
#if defined(__has_builtin)
#if __has_builtin(__builtin_amdgcn_global_load_lds)
#define HAVE_GLL 1
#endif
#endif
__device__ __forceinline__ void stage_tile(
    const unsigned short* __restrict__ src, int row_base, int row_max,
    int kb, unsigned short* lds, int wave, int lane)
{
  #pragma unroll
  for (int c = 0; c < 4; ++c) {
    const int chunk = wave * 4 + c;                    // 0..15 (wave-uniform)
    const int r = chunk * 8 + (lane >> 3);             // LDS row 0..127
    int gr = row_base + r; if (gr > row_max) gr = row_max;
    const int scb = (lane & 7) ^ ((lane >> 3) & 7);    // swizzled source col-block
    const unsigned short* gp = src + (size_t)gr * HIDDEN + kb * 64 + scb * 8;
#ifdef HAVE_GLL
    __builtin_amdgcn_global_load_lds(
        (const __attribute__((address_space(1))) void*)gp,
        (__attribute__((address_space(3))) void*)(lds + chunk * 512),
        16, 0, 0);
#else
    *(short8*)(lds + chunk * 512 + lane * 8) = *(const short8*)gp;
#endif
  }
}

// generic 128x128 block-tile MFMA core. acc[i][j] over 4x4 16x16 tiles.
// wave w: rows (w&1)*64, cols (w>>1)*64 of the block tile.
#define GEMM_CORE(A_SRC, AROWB, AROWM, B_SRC, BROWB, BROWM)                          \
  __shared__ unsigned short sA[8192], sB[8192];                                      \
  const int wave = threadIdx.x >> 6, lane = threadIdx.x & 63;                        \
  const int lrow = lane & 15, quad = lane >> 4;                                      \
  const int wr0 = (wave & 1) * 64, wc0 = (wave >> 1) * 64;                           \
  f32x4 acc[4][4];                                                                   \
  _Pragma("unroll")                                                                  \
  for (int i = 0; i < 4; ++i)                                                        \
    _Pragma("unroll")                                                                \
    for (int j = 0; j < 4; ++j) acc[i][j] = (f32x4){0.f, 0.f, 0.f, 0.f};            \
  for (int kb = 0; kb < 4; ++kb) {                                                   \
    if (kb) __syncthreads();                                                         \
    stage_tile(A_SRC, AROWB, AROWM, kb, sA, wave, lane);                             \
    stage_tile(B_SRC, BROWB, BROWM, kb, sB, wave, lane);                             \
    __syncthreads();                                                                 \
    _Pragma("unroll")                                                                \
    for (int kk = 0; kk < 2; ++kk) {                                                 \
      short8 af[4], bf[4];                                                           \
      _Pragma("unroll")                                                              \
      for (int i = 0; i < 4; ++i) {                                                  \
        const int rr = wr0 + i * 16 + lrow;                                          \
        af[i] = *(const short8*)(sA + rr * 64 + (((kk * 4 + quad) ^ (lrow & 7)) * 8));\
      }                                                                              \
      _Pragma("unroll")                                                              \
      for (int j = 0; j < 4; ++j) {                                                  \
        const int rr = wc0 + j * 16 + lrow;                                          \
        bf[j] = *(const short8*)(sB + rr * 64 + (((kk * 4 + quad) ^ (lrow & 7)) * 8));\
      }                                                                              \
      _Pragma("unroll")                                                              \
      for (int i = 0; i < 4; ++i)                                                    \
        _Pragma("unroll")                                                            \
        for (int j = 0; j < 4; ++j)                                                  \
          acc[i][j] = __builtin_amdgcn_mfma_f32_16x16x32_bf16(af[i], bf[j], acc[i][j], 0, 0, 0); \
    }                                                                                \
  }

// QKV fused: C[50000, 768] = Hc @ WQKV^T (+bias)(*scale for Q cols).
// WQKV = WqP|WkP|WvP contiguous [768][256]; bias = bqP|bkP|bvP [768].
// Output routing: col g: m=g>>8, f=g&255 -> Qt (ld 256) / KV K (ld 512) / KV V (+256).
__global__ __launch_bounds__(256) void gemm_qkv(
    const unsigned short* __restrict__ X, const unsigned short* __restrict__ WQKV,
    const unsigned short* __restrict__ biasAll,
    unsigned short* __restrict__ Qt, unsigned short* __restrict__ KV, float qscale)
{
  const int row0 = blockIdx.x * 128;
  const int col0 = blockIdx.y * 128;
  GEMM_CORE(X, row0, N_NODES - 1, WQKV, col0, 767)

  #pragma unroll
  for (int j = 0; j < 4; ++j) {
    const int gcol = col0 + wc0 + j * 16;          // multiple of 16
    const int m = gcol >> 8;
    const int f = (gcol & 255) + lrow;
    const float scale = (m == 0) ? qscale : 1.0f;
    const float bv = b2f(biasAll[gcol + lrow]);
    unsigned short* bp = (m == 0) ? Qt : (KV + ((m == 2) ? 256 : 0));
    const int ldv = (m == 0) ? 256 : KVSTRIDE;
    #pragma unroll
    for (int i = 0; i < 4; ++i) {
      #pragma unroll
      for (int r = 0; r < 4; ++r) {
        const int row = row0 + wr0 + i * 16 + quad * 4 + r;
        if (row < N_NODES)
          bp[(size_t)row * ldv + f] = f2b((acc[i][j][r] + bv) * scale);
      }
    }
  }
}

// O-projection: C[50000, 256] = pre @ WoP^T + bo; out fp32/bf16 per flags[0].
__global__ __launch_bounds__(256) void gemm_o(
    const unsigned short* __restrict__ X, const unsigned short* __restrict__ W,
    const unsigned short* __restrict__ bias, void* __restrict__ Yv,
    const int* __restrict__ flags)
{
  const int row0 = blockIdx.x * 128;
  const int col0 = blockIdx.y * 128;
  const int out_fp32 = flags[0];
  GEMM_CORE(X, row0, N_NODES - 1, W, col0, 255)

  #pragma unroll
  for (int j = 0; j < 4; ++j) {
    const int col = col0 + wc0 + j * 16 + lrow;
    const float bv = b2f(bias[col]);
    #pragma unroll
    for (int i = 0; i < 4; ++i) {
      #pragma unroll
      for (int r = 0; r < 4; ++r) {
        const int row = row0 + wr0 + i * 16 + quad * 4 + r;
        if (row < N_NODES) {
          const float y = acc[i][j][r] + bv;
          if (out_fp32) ((float*)Yv)[(size_t)row * HIDDEN + col] = y;
          else ((unsigned short*)Yv)[(size_t)row * HIDDEN + col] = f2b(y);
        }
      }
    }
  }
}

// Fused SDDMM + exp + SPMM, normalization in epilogue. One wave per node.
// KV interleaved: node n -> [K row 256 | V row 256] at KV + n*512.
// Lane l owns head-major dims [4l,4l+4) (head = l>>3). Zero LDS/barriers.
__global__ __launch_bounds__(256) void attn_fused(
    const unsigned short* __restrict__ Qt, const unsigned short* __restrict__ KV,
    const int* __restrict__ cursor, const int* __restrict__ bucket,
    unsigned short* __restrict__ pre)
{
  const int node = blockIdx.x * 4 + (threadIdx.x >> 6);
  if (node >= N_NODES) return;
  const int lane = threadIdx.x & 63;
  int cnt = cursor[node]; if (cnt > MAXDEG) cnt = MAXDEG;
  const int* brow = bucket + node * MAXDEG;

  const ushort4 qv = *(const ushort4*)(Qt + (size_t)node * HIDDEN + lane * 4);
  const float q0 = b2f(qv.x), q1 = b2f(qv.y), q2 = b2f(qv.z), q3 = b2f(qv.w);

  float a0 = 0.f, a1 = 0.f, a2 = 0.f, a3 = 0.f, z = 0.f;

  if (cnt > 0) {
    const int last = cnt - 1;
    int c0 = brow[0];
    int c1 = brow[1 <= last ? 1 : last];
    ushort4 k0 = *(const ushort4*)(KV + (size_t)c0 * KVSTRIDE + lane * 4);
    ushort4 v0 = *(const ushort4*)(KV + (size_t)c0 * KVSTRIDE + 256 + lane * 4);
    ushort4 k1 = *(const ushort4*)(KV + (size_t)c1 * KVSTRIDE + lane * 4);
    ushort4 v1 = *(const ushort4*)(KV + (size_t)c1 * KVSTRIDE + 256 + lane * 4);

    int j = 0;
    for (; j + 2 <= cnt; j += 2) {
      const int c2 = brow[j + 2 <= last ? j + 2 : last];
      const int c3 = brow[j + 3 <= last ? j + 3 : last];
      const ushort4 k2 = *(const ushort4*)(KV + (size_t)c2 * KVSTRIDE + lane * 4);
      const ushort4 v2 = *(const ushort4*)(KV + (size_t)c2 * KVSTRIDE + 256 + lane * 4);
      const ushort4 k3 = *(const ushort4*)(KV + (size_t)c3 * KVSTRIDE + lane * 4);
      const ushort4 v3 = *(const ushort4*)(KV + (size_t)c3 * KVSTRIDE + 256 + lane * 4);

      float dA = q0 * b2f(k0.x) + q1 * b2f(k0.y) + q2 * b2f(k0.z) + q3 * b2f(k0.w);
      float dB = q0 * b2f(k1.x) + q1 * b2f(k1.y) + q2 * b2f(k1.z) + q3 * b2f(k1.w);
      dA += __shfl_xor(dA, 1, 64);  dB += __shfl_xor(dB, 1, 64);
      dA += __shfl_xor(dA, 2, 64);  dB += __shfl_xor(dB, 2, 64);
      dA += __shfl_xor(dA, 4, 64);  dB += __shfl_xor(dB, 4, 64);
      const float wA = __expf(dA);
      const float wB = __expf(dB);
      z  += wA + wB;
      a0 += wA * b2f(v0.x) + wB * b2f(v1.x);
      a1 += wA * b2f(v0.y) + wB * b2f(v1.y);
      a2 += wA * b2f(v0.z) + wB * b2f(v1.z);
      a3 += wA * b2f(v0.w) + wB * b2f(v1.w);

      k0 = k2; v0 = v2; k1 = k3; v1 = v3;
    }
    if (j < cnt) {   // odd tail
      float dA = q0 * b2f(k0.x) + q1 * b2f(k0.y) + q2 * b2f(k0.z) + q3 * b2f(k0.w);
      dA += __shfl_xor(dA, 1, 64);
      dA += __shfl_xor(dA, 2, 64);
      dA += __shfl_xor(dA, 4, 64);
      const float wA = __expf(dA);
      z  += wA;
      a0 += wA * b2f(v0.x); a1 += wA * b2f(v0.y);
      a2 += wA * b2f(v0.z); a3 += wA * b2f(v0.w);
    }
  }

  const float zi = (z > 0.f) ? (1.f / z) : 0.f;
  ushort4 o;
  o.x = f2b(a0 * zi); o.y = f2b(a1 * zi); o.z = f2b(a2 * zi); o.w = f2b(a3 * zi);
  *(ushort4*)(pre + (size_t)node * HIDDEN + lane * 4) = o;
}

extern "C" void kernel_launch(void* const* d_in, const int* in_sizes, int n_in,
                              void* d_out, int out_size, void* d_ws, size_t ws_size,
                              hipStream_t stream) {
  const void* h_raw  = d_in[0];
  const int* row_raw = (const int*)d_in[1];
  const int* col_raw = (const int*)d_in[2];
  const void* Wq_raw = d_in[3]; const void* bq_raw = d_in[4];
  const void* Wk_raw = d_in[5]; const void* bk_raw = d_in[6];
  const void* Wv_raw = d_in[7]; const void* bv_raw = d_in[8];
  const void* Wo_raw = d_in[9]; const void* bo_raw = d_in[10];

  char* ws = (char*)d_ws;
  unsigned short* Qt   = (unsigned short*)(ws +          0);  // 25.6 MB
  unsigned short* KV   = (unsigned short*)(ws +  25600000);   // 51.2 MB interleaved K|V
  int*            cur  = (int*)           (ws +  76800000);   // 0.2 MB
  int*            bkt  = (int*)           (ws +  77000000);   // 12.8 MB
  unsigned short* pre  = (unsigned short*)(ws +  89800000);   // 25.6 MB
  unsigned short* WqP  = (unsigned short*)(ws + 115400000);   // 4 x 128 KB, contiguous
  unsigned short* WkP  = WqP + 65536;                         //  -> WQKV = WqP [768][256]
  unsigned short* WvP  = WkP + 65536;
  unsigned short* WoP  = WvP + 65536;
  unsigned short* bqP  = (unsigned short*)(ws + 116000000);   // 3 x 256 contiguous = biasAll
  unsigned short* bkP  = bqP + 256;
  unsigned short* bvP  = bkP + 256;
  unsigned short* boC  = bvP + 256;
  int*            flags = (int*)(ws + 116100000);
  unsigned short* Hc   = (unsigned short*)(ws + 117000000);   // 25.6 MB canonical bf16 h

  hipMemsetAsync(cur, 0, (size_t)N_NODES * 4, stream);

  detect<<<1, 256, 0, stream>>>((const unsigned short*)h_raw, row_raw, flags);

  conv_f4<<<6400, 256, 0, stream>>>(h_raw, Hc, N_NODES * HIDDEN / 4, flags);

  WPtrs wp;
  wp.srcW[0] = Wq_raw; wp.srcW[1] = Wk_raw; wp.srcW[2] = Wv_raw; wp.srcW[3] = Wo_raw;
  wp.dstW[0] = WqP;    wp.dstW[1] = WkP;    wp.dstW[2] = WvP;    wp.dstW[3] = WoP;
  wp.srcB[0] = bq_raw; wp.srcB[1] = bk_raw; wp.srcB[2] = bv_raw; wp.srcB[3] = bo_raw;
  wp.dstB[0] = bqP;    wp.dstB[1] = bkP;    wp.dstB[2] = bvP;    wp.dstB[3] = boC;
  conv_wb<<<(114944 + 255) / 256, 256, 0, stream>>>(wp, flags);

  build_buckets<<<(N_EDGES + 255) / 256, 256, 0, stream>>>(row_raw, col_raw, flags, cur, bkt);

  dim3 qgrid(MTILES, 6);   // N = 768 fused QKV
  gemm_qkv<<<qgrid, 256, 0, stream>>>(Hc, WqP, bqP, Qt, KV, 0.17677669529663687f);

  attn_fused<<<(N_NODES + 3) / 4, 256, 0, stream>>>(Qt, KV, cur, bkt, pre);

  dim3 ogrid(MTILES, 2);   // N = 256
  gemm_o<<<ogrid, 256, 0, stream>>>(pre, WoP, boC, d_out, flags);
}